// Round 5
// baseline (55.574 us; speedup 1.0000x reference)
//
#include <hip/hip_runtime.h>

#define PS     25
#define PADR   12
#define EPSV   (1.0f/255.0f)
#define WW     512
#define HH     512
#define NB     16
#define TS     8             // output rows per wave (halved: 2x waves/CU)
#define INV625 (1.0f/625.0f)

__device__ __forceinline__ int reflectI(int i, int n) {
    if (i < 0)  i = -i;
    if (i >= n) i = 2 * n - 2 - i;
    return i;
}

__device__ __forceinline__ float fastrcp(float x) {
    float y;
    asm("v_rcp_f32 %0, %1" : "=v"(y) : "v"(x));
    return y;
}

// load 4 raw rgb values (reflect-handled cols) for row ry starting at col c0
__device__ __forceinline__ void loadRGB(const float* __restrict__ pR,
                                        const float* __restrict__ pG,
                                        const float* __restrict__ pB,
                                        int ry, int c0, bool vecOK,
                                        float r[4], float g[4], float b[4])
{
    const size_t ro = (size_t)ry * WW;
    if (vecOK) {
        float4 a = *(const float4*)(pR + ro + c0);
        float4 c = *(const float4*)(pG + ro + c0);
        float4 d = *(const float4*)(pB + ro + c0);
        r[0]=a.x; r[1]=a.y; r[2]=a.z; r[3]=a.w;
        g[0]=c.x; g[1]=c.y; g[2]=c.z; g[3]=c.w;
        b[0]=d.x; b[1]=d.y; b[2]=d.z; b[3]=d.w;
    } else {
#pragma unroll
        for (int j = 0; j < 4; ++j) {
            int cc = reflectI(c0 + j, WW);
            r[j] = pR[ro + cc];
            g[j] = pG[ro + cc];
            b[j] = pB[ro + cc];
        }
    }
}

__device__ __forceinline__ void computeMS(const float* __restrict__ pR,
                                          const float* __restrict__ pG,
                                          const float* __restrict__ pB,
                                          int ry, int c0, bool vecOK,
                                          float m[4], float s[4])
{
    float r[4], g[4], b[4];
    loadRGB(pR, pG, pB, ry, c0, vecOK, r, g, b);
#pragma unroll
    for (int j = 0; j < 4; ++j) {
        m[j] = (r[j] + g[j] + b[j]) * (1.0f/3.0f);
        s[j] = fmaf(r[j], r[j], fmaf(g[j], g[j], b[j]*b[j])) * (1.0f/3.0f);
    }
}

// 1 wave (64 threads) per block; each thread owns 4 consecutive columns.
// Vertical 25-tap = register running sum (subtract re-reads from LLC).
// Horizontal 25-tap via per-block LDS row buffer; NO __syncthreads anywhere.
__global__ __launch_bounds__(64)
void fused_stream(const float* __restrict__ img, float* __restrict__ out)
{
    const int t  = threadIdx.x;
    const int xt = blockIdx.x;          // 0..2  output cols {0,232,464}
    const int ys = blockIdx.y;          // 0..63 row strip
    const int b  = blockIdx.z;

    const int x0_out  = xt * 232;
    const int out_w   = (xt == 2) ? 48 : 232;
    const int need_w  = out_w + 2 * PADR;      // 256,256,72
    const int x0_load = x0_out - PADR;

    const int  c0      = x0_load + 4 * t;      // first raw col of this thread (halo frame)
    const int  cs0     = c0 + PADR;            // first OUTPUT col of this thread
    const bool activeL = (4 * t < need_w);
    const bool doOut   = (4 * t < out_w);
    const bool vecOK   = (c0 >= 0) && (c0 + 3 < WW);

    if (!activeL) return;                      // safe: no barriers in kernel

    __shared__ float vmRow[260];
    __shared__ float vsRow[260];

    const size_t plane = (size_t)WW * HH;
    const float* pR = img + (size_t)b * 3 * plane;
    const float* pG = pR + plane;
    const float* pB = pR + 2 * plane;

    const int r0 = ys * TS;

    // ---- prologue: vertical sums over window of first output row ----
    float vm[4] = {0,0,0,0}, vs[4] = {0,0,0,0};
    for (int k = -PADR; k <= PADR; ++k) {
        float m[4], s[4];
        computeMS(pR, pG, pB, reflectI(r0 + k, HH), c0, vecOK, m, s);
#pragma unroll
        for (int j = 0; j < 4; ++j) { vm[j] += m[j]; vs[j] += s[j]; }
    }

    // ---- steady loop over output rows ----
#pragma unroll 2
    for (int yo = r0; yo < r0 + TS; ++yo) {
        // incoming row (fresh, HBM) and outgoing row (LLC re-read)
        float mi[4], si[4], mo[4], so[4];
        computeMS(pR, pG, pB, reflectI(yo + PADR + 1, HH), c0, vecOK, mi, si);
        computeMS(pR, pG, pB, reflectI(yo - PADR,     HH), c0, vecOK, mo, so);

        // publish vertical sums for this row
        *(float4*)&vmRow[4*t] = make_float4(vm[0], vm[1], vm[2], vm[3]);
        *(float4*)&vsRow[4*t] = make_float4(vs[0], vs[1], vs[2], vs[3]);

        if (doOut) {
            // saturation at this thread's OUTPUT columns (cs0..cs0+3),
            // always in-bounds and 16B-aligned for doOut lanes
            const size_t ro = (size_t)yo * WW;
            float4 ra = *(const float4*)(pR + ro + cs0);
            float4 ga = *(const float4*)(pG + ro + cs0);
            float4 ba = *(const float4*)(pB + ro + cs0);
            float r[4] = {ra.x, ra.y, ra.z, ra.w};
            float g[4] = {ga.x, ga.y, ga.z, ga.w};
            float bb[4] = {ba.x, ba.y, ba.z, ba.w};
            float sat[4];
#pragma unroll
            for (int j = 0; j < 4; ++j) {
                float mx = fmaxf(r[j], fmaxf(g[j], bb[j]));
                float mn = fminf(r[j], fminf(g[j], bb[j]));
                sat[j] = (mx - mn + EPSV) * fastrcp(mx + EPSV);
            }

            // read 28-float windows (7 x b128 per array), in-wave ordering
            float wm[28], ws[28];
#pragma unroll
            for (int i = 0; i < 7; ++i) {
                float4 a = *(const float4*)&vmRow[4*t + 4*i];
                float4 c = *(const float4*)&vsRow[4*t + 4*i];
                wm[4*i]=a.x; wm[4*i+1]=a.y; wm[4*i+2]=a.z; wm[4*i+3]=a.w;
                ws[4*i]=c.x; ws[4*i+1]=c.y; ws[4*i+2]=c.z; ws[4*i+3]=c.w;
            }
            float hm = 0.f, hs = 0.f;
#pragma unroll
            for (int i = 0; i < PS; ++i) { hm += wm[i]; hs += ws[i]; }

            float sc[4];
#pragma unroll
            for (int j = 0; j < 4; ++j) {
                if (j > 0) {
                    hm += wm[PS - 1 + j] - wm[j - 1];
                    hs += ws[PS - 1 + j] - ws[j - 1];
                }
                float mean     = hm * INV625;
                float msq      = hs * INV625;
                float contrast = fmaf(-mean, mean, msq);
                float expo     = fabsf(mean - 0.5f) + EPSV;
                sc[j] = sat[j] * contrast * fastrcp(expo);
            }
            float* orow = out + ((size_t)b * HH + yo) * WW + x0_out + 4*t;
            *(float4*)orow = make_float4(sc[0], sc[1], sc[2], sc[3]);
        }

        // slide the vertical window
#pragma unroll
        for (int j = 0; j < 4; ++j) {
            vm[j] += mi[j] - mo[j];
            vs[j] += si[j] - so[j];
        }
    }
}

extern "C" void kernel_launch(void* const* d_in, const int* in_sizes, int n_in,
                              void* d_out, int out_size, void* d_ws, size_t ws_size,
                              hipStream_t stream)
{
    const float* img = (const float*)d_in[0];
    float* out = (float*)d_out;

    dim3 grid(3, HH / TS, NB);     // 3 x-tiles, 64 row strips, 16 images
    fused_stream<<<grid, 64, 0, stream>>>(img, out);
}

// Round 6
// 40.417 us; speedup vs baseline: 1.3750x; 1.3750x over previous
//
#include <hip/hip_runtime.h>

#define PS    25
#define PADW  12
#define EPSV  (1.0f/255.0f)
#define WW    512
#define HH    512
#define NB    16

#define TW    64              // output tile width
#define TH    16              // output tile height
#define IWn   (TW + 2*PADW)   // 88 halo cols loaded
#define IHn   (TH + 2*PADW + 1) // 40 halo rows loaded (16+24)
#define IWS   89              // LDS stride (odd -> bank spread)
#define NPX   (IWn * IHn)     // 3520 halo pixels

#define INV625 (1.0f/625.0f)

__device__ __forceinline__ int reflectI(int i, int n) {
    if (i < 0)  i = -i;
    if (i >= n) i = 2 * n - 2 - i;
    return i;
}

__device__ __forceinline__ float fastrcp(float x) {
    float y;
    asm("v_rcp_f32 %0, %1" : "=v"(y) : "v"(x));
    return y;
}

__global__ __launch_bounds__(256, 4)
void fused_tile(const float* __restrict__ img, float* __restrict__ out)
{
    const int t  = threadIdx.x;
    const int x0 = blockIdx.x * TW;
    const int y0 = blockIdx.y * TH;
    const int b  = blockIdx.z;

    __shared__ float smM[IHn][IWS];   // channel-mean            (40x89)
    __shared__ float smS[IHn][IWS];   // channel-mean of squares (40x89)
    __shared__ float vM[TH][IWS];     // vertical 25-tap sums    (16x89)
    __shared__ float vS[TH][IWS];

    const size_t plane = (size_t)WW * HH;
    const float* pR = img + (size_t)b * 3 * plane;
    const float* pG = pR + plane;
    const float* pB = pR + 2 * plane;

    // ---- stage 1: load halo (88x40), compute m,s into LDS ----
    for (int i = t; i < NPX; i += 256) {
        int iy = i / IWn;
        int ix = i - iy * IWn;
        int gy = reflectI(y0 - PADW + iy, HH);
        int gx = reflectI(x0 - PADW + ix, WW);
        size_t idx = (size_t)gy * WW + gx;
        float r  = pR[idx];
        float g  = pG[idx];
        float bl = pB[idx];
        smM[iy][ix] = (r + g + bl) * (1.0f/3.0f);
        smS[iy][ix] = fmaf(r, r, fmaf(g, g, bl*bl)) * (1.0f/3.0f);
    }
    __syncthreads();

    // ---- stage 2: vertical 25-tap incremental scan (176 tasks) ----
    if (t < 2 * IWn) {
        const int x   = (t < IWn) ? t : t - IWn;
        const float (*src)[IWS] = (t < IWn) ? smM : smS;
        float (*dst)[IWS]       = (t < IWn) ? vM  : vS;
        float sum = 0.f;
#pragma unroll
        for (int k = 0; k < PS; ++k) sum += src[k][x];
        dst[0][x] = sum;
#pragma unroll
        for (int y = 1; y < TH; ++y) {
            sum += src[y + PS - 1][x] - src[y - 1][x];
            dst[y][x] = sum;
        }
    }
    __syncthreads();

    // ---- stage 3: horizontal 25-tap + sat + final (all 256 threads) ----
    const int r  = t >> 4;          // 0..15 output row
    const int c4 = (t & 15) * 4;    // 0..60 output col group

    // window of 28 vertical sums starting at LDS x = c4 (aligned b128)
    float wm[28], ws[28];
#pragma unroll
    for (int i = 0; i < 7; ++i) {
        float4 a = *(const float4*)&vM[r][c4 + 4*i];
        float4 c = *(const float4*)&vS[r][c4 + 4*i];
        wm[4*i]=a.x; wm[4*i+1]=a.y; wm[4*i+2]=a.z; wm[4*i+3]=a.w;
        ws[4*i]=c.x; ws[4*i+1]=c.y; ws[4*i+2]=c.z; ws[4*i+3]=c.w;
    }
    float hm = 0.f, hs = 0.f;
#pragma unroll
    for (int i = 0; i < PS; ++i) { hm += wm[i]; hs += ws[i]; }

    // saturation: re-read this thread's 4 output pixels (L2-hot from stage 1)
    const size_t ro = (size_t)(y0 + r) * WW + x0 + c4;
    float4 ra = *(const float4*)(pR + ro);
    float4 ga = *(const float4*)(pG + ro);
    float4 ba = *(const float4*)(pB + ro);
    float rr[4] = {ra.x, ra.y, ra.z, ra.w};
    float gg[4] = {ga.x, ga.y, ga.z, ga.w};
    float bb[4] = {ba.x, ba.y, ba.z, ba.w};

    float sc[4];
#pragma unroll
    for (int j = 0; j < 4; ++j) {
        if (j > 0) {
            hm += wm[PS - 1 + j] - wm[j - 1];
            hs += ws[PS - 1 + j] - ws[j - 1];
        }
        float mx = fmaxf(rr[j], fmaxf(gg[j], bb[j]));
        float mn = fminf(rr[j], fminf(gg[j], bb[j]));
        float sat = (mx - mn + EPSV) * fastrcp(mx + EPSV);

        float mean     = hm * INV625;
        float msq      = hs * INV625;
        float contrast = fmaf(-mean, mean, msq);
        float expo     = fabsf(mean - 0.5f) + EPSV;
        sc[j] = sat * contrast * fastrcp(expo);
    }
    float* orow = out + ((size_t)b * HH + (y0 + r)) * WW + x0 + c4;
    *(float4*)orow = make_float4(sc[0], sc[1], sc[2], sc[3]);
}

extern "C" void kernel_launch(void* const* d_in, const int* in_sizes, int n_in,
                              void* d_out, int out_size, void* d_ws, size_t ws_size,
                              hipStream_t stream)
{
    const float* img = (const float*)d_in[0];
    float* out = (float*)d_out;

    dim3 grid(WW / TW, HH / TH, NB);   // 8 x 32 x 16 = 4096 blocks
    fused_tile<<<grid, 256, 0, stream>>>(img, out);
}

// Round 7
// 36.043 us; speedup vs baseline: 1.5419x; 1.1214x over previous
//
#include <hip/hip_runtime.h>

#define PS    25
#define PADW  12
#define EPSV  (1.0f/255.0f)
#define WW    512
#define HH    512
#define NB    16

#define TW    64                 // output tile width
#define TH    16                 // output tile height
#define IWn   (TW + 2*PADW)      // 88 halo cols
#define IHn   (TH + 2*PADW + 1)  // 40 halo rows
#define IWS   92                 // LDS stride (mult of 4 -> b128-aligned)
#define NPX   (IWn * IHn)        // 3520 halo pixels (scalar path)
#define NPX4  (IHn * (IWn/4))    // 880 float4 groups (fast path)

#define INV625 (1.0f/625.0f)

__device__ __forceinline__ int reflectI(int i, int n) {
    if (i < 0)  i = -i;
    if (i >= n) i = 2 * n - 2 - i;
    return i;
}

__device__ __forceinline__ float fastrcp(float x) {
    float y;
    asm("v_rcp_f32 %0, %1" : "=v"(y) : "v"(x));
    return y;
}

__global__ __launch_bounds__(256, 5)
void fused_tile(const float* __restrict__ img, float* __restrict__ out)
{
    const int t  = threadIdx.x;
    const int x0 = blockIdx.x * TW;
    const int y0 = blockIdx.y * TH;
    const int b  = blockIdx.z;

    // rows 0..15 are overwritten by the vertical 25-tap sums in stage 2
    __shared__ float smM[IHn][IWS];   // channel-mean            (40x92)
    __shared__ float smS[IHn][IWS];   // channel-mean of squares (40x92)

    const size_t plane = (size_t)WW * HH;
    const float* pR = img + (size_t)b * 3 * plane;
    const float* pG = pR + plane;
    const float* pB = pR + 2 * plane;

    const bool interior = (x0 >= TW) && (x0 + TW + PADW <= WW) &&
                          (y0 >= TH) && (y0 + TH + PADW <= HH);

    // ---- stage 1: load halo, compute m,s into LDS ----
    if (interior) {
        // fully in-bounds: vectorized float4 path
        const size_t base = (size_t)(y0 - PADW) * WW + (x0 - PADW);
        for (int i = t; i < NPX4; i += 256) {
            int iy = i / (IWn/4);              // 0..39
            int ix = (i - iy * (IWn/4)) * 4;   // 0,4,...,84
            size_t off = base + (size_t)(iy << 9) + ix;
            float4 ra = *(const float4*)(pR + off);
            float4 ga = *(const float4*)(pG + off);
            float4 ba = *(const float4*)(pB + off);
            float m[4], s[4];
            float r[4] = {ra.x, ra.y, ra.z, ra.w};
            float g[4] = {ga.x, ga.y, ga.z, ga.w};
            float bl[4] = {ba.x, ba.y, ba.z, ba.w};
#pragma unroll
            for (int j = 0; j < 4; ++j) {
                m[j] = (r[j] + g[j] + bl[j]) * (1.0f/3.0f);
                s[j] = fmaf(r[j], r[j], fmaf(g[j], g[j], bl[j]*bl[j])) * (1.0f/3.0f);
            }
            *(float4*)&smM[iy][ix] = make_float4(m[0], m[1], m[2], m[3]);
            *(float4*)&smS[iy][ix] = make_float4(s[0], s[1], s[2], s[3]);
        }
    } else {
        // edge tiles: scalar reflect path
        for (int i = t; i < NPX; i += 256) {
            int iy = i / IWn;
            int ix = i - iy * IWn;
            int gy = reflectI(y0 - PADW + iy, HH);
            int gx = reflectI(x0 - PADW + ix, WW);
            size_t idx = (size_t)gy * WW + gx;
            float r  = pR[idx];
            float g  = pG[idx];
            float bl = pB[idx];
            smM[iy][ix] = (r + g + bl) * (1.0f/3.0f);
            smS[iy][ix] = fmaf(r, r, fmaf(g, g, bl*bl)) * (1.0f/3.0f);
        }
    }
    __syncthreads();

    // ---- stage 2: vertical 25-tap incremental scan, IN-PLACE into rows 0..15 ----
    if (t < 2 * IWn) {
        const int x = (t < IWn) ? t : t - IWn;
        float (*buf)[IWS] = (t < IWn) ? smM : smS;
        float sum = 0.f, old0;
#pragma unroll
        for (int k = 0; k < PS; ++k) {
            float v = buf[k][x];
            if (k == 0) old0 = v;
            sum += v;
        }
        float prev_old = old0;
        buf[0][x] = sum;
#pragma unroll
        for (int y = 1; y < TH; ++y) {
            float cur_old = buf[y][x];             // original m/s value
            sum += buf[y + PS - 1][x] - prev_old;  // slide window
            buf[y][x] = sum;                       // publish vertical sum
            prev_old = cur_old;
        }
    }
    __syncthreads();

    // ---- stage 3: horizontal 25-tap + sat + final (all 256 threads) ----
    const int r  = t >> 4;          // 0..15 output row
    const int c4 = (t & 15) * 4;    // 0..60 output col group

    float wm[28], ws[28];
#pragma unroll
    for (int i = 0; i < 7; ++i) {
        float4 a = *(const float4*)&smM[r][c4 + 4*i];
        float4 c = *(const float4*)&smS[r][c4 + 4*i];
        wm[4*i]=a.x; wm[4*i+1]=a.y; wm[4*i+2]=a.z; wm[4*i+3]=a.w;
        ws[4*i]=c.x; ws[4*i+1]=c.y; ws[4*i+2]=c.z; ws[4*i+3]=c.w;
    }
    float hm = 0.f, hs = 0.f;
#pragma unroll
    for (int i = 0; i < PS; ++i) { hm += wm[i]; hs += ws[i]; }

    // saturation: re-read this thread's 4 output pixels (L2-hot from stage 1)
    const size_t ro = (size_t)(y0 + r) * WW + x0 + c4;
    float4 ra = *(const float4*)(pR + ro);
    float4 ga = *(const float4*)(pG + ro);
    float4 ba = *(const float4*)(pB + ro);
    float rr[4] = {ra.x, ra.y, ra.z, ra.w};
    float gg[4] = {ga.x, ga.y, ga.z, ga.w};
    float bb[4] = {ba.x, ba.y, ba.z, ba.w};

    float sc[4];
#pragma unroll
    for (int j = 0; j < 4; ++j) {
        if (j > 0) {
            hm += wm[PS - 1 + j] - wm[j - 1];
            hs += ws[PS - 1 + j] - ws[j - 1];
        }
        float mx = fmaxf(rr[j], fmaxf(gg[j], bb[j]));
        float mn = fminf(rr[j], fminf(gg[j], bb[j]));
        float sat = (mx - mn + EPSV) * fastrcp(mx + EPSV);

        float mean     = hm * INV625;
        float msq      = hs * INV625;
        float contrast = fmaf(-mean, mean, msq);
        float expo     = fabsf(mean - 0.5f) + EPSV;
        sc[j] = sat * contrast * fastrcp(expo);
    }
    float* orow = out + ((size_t)b * HH + (y0 + r)) * WW + x0 + c4;
    *(float4*)orow = make_float4(sc[0], sc[1], sc[2], sc[3]);
}

extern "C" void kernel_launch(void* const* d_in, const int* in_sizes, int n_in,
                              void* d_out, int out_size, void* d_ws, size_t ws_size,
                              hipStream_t stream)
{
    const float* img = (const float*)d_in[0];
    float* out = (float*)d_out;

    dim3 grid(WW / TW, HH / TH, NB);   // 8 x 32 x 16 = 4096 blocks
    fused_tile<<<grid, 256, 0, stream>>>(img, out);
}

// Round 8
// 30.083 us; speedup vs baseline: 1.8474x; 1.1981x over previous
//
#include <hip/hip_runtime.h>

#define PS    25
#define PADW  12
#define EPSV  (1.0f/255.0f)
#define WW    512
#define HH    512
#define NB    16

#define TW    64                 // output tile width
#define TH    32                 // output tile height
#define IWn   (TW + 2*PADW)      // 88 halo cols
#define IHn   (TH + 2*PADW)      // 56 halo rows (TH+24 needed, exactly)
#define IWS   88                 // LDS stride (mult of 4, minimal)
#define NPX   (IWn * IHn)        // 4928 halo pixels (scalar path)
#define NPX4  (IHn * (IWn/4))    // 1232 float4 groups (fast path)
#define SEGR  16                 // rows per stage-2 segment
#define NTASK (2 * IWn * 2)      // 352 stage-2 tasks

#define INV625 (1.0f/625.0f)

__device__ __forceinline__ int reflectI(int i, int n) {
    if (i < 0)  i = -i;
    if (i >= n) i = 2 * n - 2 - i;
    return i;
}

__device__ __forceinline__ float fastrcp(float x) {
    float y;
    asm("v_rcp_f32 %0, %1" : "=v"(y) : "v"(x));
    return y;
}

__global__ __launch_bounds__(512, 8)
void fused_tile(const float* __restrict__ img, float* __restrict__ out)
{
    const int t  = threadIdx.x;
    const int x0 = blockIdx.x * TW;
    const int y0 = blockIdx.y * TH;
    const int b  = blockIdx.z;

    // rows 0..31 get overwritten by vertical 25-tap sums (after a barrier)
    __shared__ float smM[IHn][IWS];   // channel-mean            (56x88)
    __shared__ float smS[IHn][IWS];   // channel-mean of squares (56x88)

    const size_t plane = (size_t)WW * HH;
    const float* pR = img + (size_t)b * 3 * plane;
    const float* pG = pR + plane;
    const float* pB = pR + 2 * plane;

    const bool interior = (x0 >= PADW) && (x0 + TW + PADW <= WW) &&
                          (y0 >= PADW) && (y0 + TH + PADW <= HH);

    // ---- stage 1: load halo, compute m,s into LDS ----
    if (interior) {
        const size_t base = (size_t)(y0 - PADW) * WW + (x0 - PADW);
        for (int i = t; i < NPX4; i += 512) {
            int iy = i / (IWn/4);              // 0..55
            int ix = (i - iy * (IWn/4)) * 4;   // 0,4,...,84
            size_t off = base + (size_t)(iy << 9) + ix;
            float4 ra = *(const float4*)(pR + off);
            float4 ga = *(const float4*)(pG + off);
            float4 ba = *(const float4*)(pB + off);
            float r[4]  = {ra.x, ra.y, ra.z, ra.w};
            float g[4]  = {ga.x, ga.y, ga.z, ga.w};
            float bl[4] = {ba.x, ba.y, ba.z, ba.w};
            float m[4], s[4];
#pragma unroll
            for (int j = 0; j < 4; ++j) {
                m[j] = (r[j] + g[j] + bl[j]) * (1.0f/3.0f);
                s[j] = fmaf(r[j], r[j], fmaf(g[j], g[j], bl[j]*bl[j])) * (1.0f/3.0f);
            }
            *(float4*)&smM[iy][ix] = make_float4(m[0], m[1], m[2], m[3]);
            *(float4*)&smS[iy][ix] = make_float4(s[0], s[1], s[2], s[3]);
        }
    } else {
        for (int i = t; i < NPX; i += 512) {
            int iy = i / IWn;
            int ix = i - iy * IWn;
            int gy = reflectI(y0 - PADW + iy, HH);
            int gx = reflectI(x0 - PADW + ix, WW);
            size_t idx = (size_t)gy * WW + gx;
            float r  = pR[idx];
            float g  = pG[idx];
            float bl = pB[idx];
            smM[iy][ix] = (r + g + bl) * (1.0f/3.0f);
            smS[iy][ix] = fmaf(r, r, fmaf(g, g, bl*bl)) * (1.0f/3.0f);
        }
    }
    __syncthreads();

    // ---- stage 2a: vertical 25-tap sums into REGISTERS (reads only) ----
    // 352 tasks: {m,s} x {seg0 rows 0..15, seg1 rows 16..31} x 88 cols
    float sums[SEGR];
    int   s2x = 0, s2y0 = 0;
    float (*s2buf)[IWS] = smM;
    const bool s2act = (t < NTASK);
    if (s2act) {
        int rem = t;
        if (rem >= 2 * IWn) { s2buf = smS; rem -= 2 * IWn; }
        if (rem >= IWn)     { s2y0 = SEGR; rem -= IWn; }
        s2x = rem;
        float run = 0.f;
#pragma unroll
        for (int k = 0; k < PS; ++k) run += s2buf[s2y0 + k][s2x];
        sums[0] = run;
#pragma unroll
        for (int y = 1; y < SEGR; ++y) {
            run += s2buf[s2y0 + y + PS - 1][s2x] - s2buf[s2y0 + y - 1][s2x];
            sums[y] = run;
        }
    }
    __syncthreads();

    // ---- stage 2b: publish vertical sums in-place (rows 0..31) ----
    if (s2act) {
#pragma unroll
        for (int y = 0; y < SEGR; ++y) s2buf[s2y0 + y][s2x] = sums[y];
    }
    __syncthreads();

    // ---- stage 3: horizontal 25-tap + sat + final (512 tasks exactly) ----
    const int r  = t >> 4;          // 0..31 output row
    const int c4 = (t & 15) * 4;    // 0..60 output col group

    float wm[28], ws[28];
#pragma unroll
    for (int i = 0; i < 7; ++i) {
        float4 a = *(const float4*)&smM[r][c4 + 4*i];
        float4 c = *(const float4*)&smS[r][c4 + 4*i];
        wm[4*i]=a.x; wm[4*i+1]=a.y; wm[4*i+2]=a.z; wm[4*i+3]=a.w;
        ws[4*i]=c.x; ws[4*i+1]=c.y; ws[4*i+2]=c.z; ws[4*i+3]=c.w;
    }
    float hm = 0.f, hs = 0.f;
#pragma unroll
    for (int i = 0; i < PS; ++i) { hm += wm[i]; hs += ws[i]; }

    // saturation: re-read this thread's 4 output pixels (L2-hot)
    const size_t ro = (size_t)(y0 + r) * WW + x0 + c4;
    float4 ra = *(const float4*)(pR + ro);
    float4 ga = *(const float4*)(pG + ro);
    float4 ba = *(const float4*)(pB + ro);
    float rr[4] = {ra.x, ra.y, ra.z, ra.w};
    float gg[4] = {ga.x, ga.y, ga.z, ga.w};
    float bb[4] = {ba.x, ba.y, ba.z, ba.w};

    float sc[4];
#pragma unroll
    for (int j = 0; j < 4; ++j) {
        if (j > 0) {
            hm += wm[PS - 1 + j] - wm[j - 1];
            hs += ws[PS - 1 + j] - ws[j - 1];
        }
        float mx = fmaxf(rr[j], fmaxf(gg[j], bb[j]));
        float mn = fminf(rr[j], fminf(gg[j], bb[j]));
        float sat = (mx - mn + EPSV) * fastrcp(mx + EPSV);

        float mean     = hm * INV625;
        float msq      = hs * INV625;
        float contrast = fmaf(-mean, mean, msq);
        float expo     = fabsf(mean - 0.5f) + EPSV;
        sc[j] = sat * contrast * fastrcp(expo);
    }
    float* orow = out + ((size_t)b * HH + (y0 + r)) * WW + x0 + c4;
    *(float4*)orow = make_float4(sc[0], sc[1], sc[2], sc[3]);
}

extern "C" void kernel_launch(void* const* d_in, const int* in_sizes, int n_in,
                              void* d_out, int out_size, void* d_ws, size_t ws_size,
                              hipStream_t stream)
{
    const float* img = (const float*)d_in[0];
    float* out = (float*)d_out;

    dim3 grid(WW / TW, HH / TH, NB);   // 8 x 16 x 16 = 2048 blocks
    fused_tile<<<grid, 512, 0, stream>>>(img, out);
}